// Round 5
// baseline (420.542 us; speedup 1.0000x reference)
//
#include <hip/hip_runtime.h>
#include <hip/hip_bf16.h>
#include <math.h>

#define NGRAPH 128
#define NPG_   512
#define NN     (NGRAPH*NPG_)     // 65536 nodes
#define EPG    504
#define ETOT   (NGRAPH*EPG)      // 64512 real edges
#define HEADS  8
#define FDIM   512
#define NEG    0.2f

typedef __hip_bfloat16 bf16;
typedef __attribute__((ext_vector_type(8))) short short8;   // 8 bf16 = 4 VGPR
typedef __attribute__((ext_vector_type(4))) float f32x4;

static __device__ __forceinline__ float bf(short s){
  union { unsigned u; float f; } c; c.u = ((unsigned)(unsigned short)s) << 16; return c.f;
}

static __device__ __forceinline__ void gload16(void* lds, const void* g){
  __builtin_amdgcn_global_load_lds((const __attribute__((address_space(1))) void*)g,
                                   (__attribute__((address_space(3))) void*)lds, 16, 0, 0);
}

// ---------------- workspace guard ----------------
__global__ void k_sentinel(float* out, int n){
  int i = blockIdx.x*blockDim.x + threadIdx.x;
  if (i < n) out[i] = 12345.0f;
}

// ---------------- CSR build ----------------
__global__ void k_zero(int* __restrict__ deg, int* __restrict__ cursor, float* __restrict__ ssum){
  int i = blockIdx.x*blockDim.x + threadIdx.x;
  if (i < NN){ deg[i]=0; cursor[i]=0; ssum[i]=0.f; }
}

__global__ void k_count(const int* __restrict__ ei, const float* __restrict__ ea,
                        int* __restrict__ deg, float* __restrict__ ssum){
  int e = blockIdx.x*blockDim.x + threadIdx.x;
  if (e >= ETOT) return;
  int g = e / EPG;
  int dst = ei[e*2+1] + g*NPG_;
  atomicAdd(&deg[dst], 1);
  atomicAdd(&ssum[dst], ea[e]);
}

__global__ __launch_bounds__(1024) void k_scan1(const int* __restrict__ deg,
                                                int* __restrict__ incl, int* __restrict__ bsum){
  __shared__ int tmp[1024];
  int t = threadIdx.x;
  int i = blockIdx.x*1024 + t;
  tmp[t] = deg[i];
  __syncthreads();
  for (int o=1;o<1024;o<<=1){
    int v = (t>=o) ? tmp[t-o] : 0;
    __syncthreads();
    tmp[t] += v;
    __syncthreads();
  }
  incl[i] = tmp[t];
  if (t==1023) bsum[blockIdx.x] = tmp[1023];
}

__global__ void k_scan2(int* __restrict__ bsum){   // 1 block, 64 threads
  __shared__ int tmp[64];
  int t = threadIdx.x;
  tmp[t] = bsum[t];
  __syncthreads();
  for (int o=1;o<64;o<<=1){
    int v = (t>=o) ? tmp[t-o] : 0;
    __syncthreads();
    tmp[t] += v;
    __syncthreads();
  }
  bsum[t] = tmp[t];
}

__global__ void k_scan3(const int* __restrict__ incl, const int* __restrict__ bsum,
                        const int* __restrict__ deg, int* __restrict__ row_ptr,
                        const float* __restrict__ ssum, float* __restrict__ la){
  int i = blockIdx.x*blockDim.x + threadIdx.x;
  if (i >= NN) return;
  int b = i >> 10;
  int off = (b>0) ? bsum[b-1] : 0;
  row_ptr[i] = incl[i] - deg[i] + off;   // exclusive prefix
  la[i] = ssum[i] / fmaxf((float)deg[i], 1.f);
}

__global__ void k_fill(const int* __restrict__ ei, const float* __restrict__ ea,
                       const int* __restrict__ row_ptr, int* __restrict__ cursor,
                       int* __restrict__ esrc, float* __restrict__ eattr){
  int e = blockIdx.x*blockDim.x + threadIdx.x;
  if (e >= ETOT) return;
  int g = e / EPG;
  int src = ei[e*2]   + g*NPG_;
  int dst = ei[e*2+1] + g*NPG_;
  int slot = atomicAdd(&cursor[dst], 1);
  int p = row_ptr[dst] + slot;
  esrc[p]  = src;
  eattr[p] = ea[e];
}

// ---------------- coefE[h] = sum_c We[h*64+c]*ae[h*64+c], 3 layers in one ----------------
__global__ __launch_bounds__(512) void k_coef3(const float* __restrict__ We0, const float* __restrict__ ae0,
                                               const float* __restrict__ We1, const float* __restrict__ ae1,
                                               const float* __restrict__ We2, const float* __restrict__ ae2,
                                               float* __restrict__ coef){
  int l = blockIdx.x;
  const float* We = l==0 ? We0 : (l==1 ? We1 : We2);
  const float* ae = l==0 ? ae0 : (l==1 ? ae1 : ae2);
  int tid = threadIdx.x;                 // 8 waves, wave per head
  float v = We[tid]*ae[tid];
  #pragma unroll
  for (int o=32;o>0;o>>=1) v += __shfl_down(v, o);
  if ((tid & 63) == 0) coef[l*HEADS + (tid>>6)] = v;
}

// ---------------- W -> transposed bf16 hi/lo split: Wt[n][k], layers 2,3 ----------------
__global__ void k_wsplit(const float* __restrict__ W1, const float* __restrict__ W2,
                         bf16* __restrict__ hi, bf16* __restrict__ lo){
  int idx = blockIdx.x*blockDim.x + threadIdx.x;     // l*256K + n*512 + k
  if (idx >= 2*FDIM*FDIM) return;
  int l = idx >> 18;
  int r = idx & (FDIM*FDIM-1);
  int n = r >> 9, k = r & 511;
  const float* W = l ? W2 : W1;
  float w = W[k*FDIM + n];                           // transposed read (L2-resident 1MB)
  bf16 h = __float2bfloat16(w);
  float rem = w - __bfloat162float(h);
  hi[idx] = h;
  lo[idx] = __float2bfloat16(rem);
}

// ---------------- layer1 linear (K=3) + attention logits fused: wave per node ----------------
__global__ __launch_bounds__(256) void k_lin1_attn(const float* __restrict__ x,
                                                   const float* __restrict__ W,
                                                   const float* __restrict__ a_s,
                                                   const float* __restrict__ a_d,
                                                   bf16* __restrict__ xs,
                                                   float* __restrict__ als,
                                                   float* __restrict__ ald){
  int n = blockIdx.x*4 + (threadIdx.x >> 6);
  int lane = threadIdx.x & 63;
  int f0 = lane << 3;
  const float* xr = x + n*3;
  float x0 = xr[0], x1 = xr[1], x2 = xr[2];
  float v[8];
  short8 r;
  #pragma unroll
  for (int j=0;j<8;j++){
    v[j] = x0*W[f0+j] + x1*W[FDIM+f0+j] + x2*W[2*FDIM+f0+j];
    bf16 b = __float2bfloat16(v[j]);
    r[j] = *(short*)&b;
  }
  ((short8*)(xs + (size_t)n*FDIM))[lane] = r;
  const float4* as4 = (const float4*)(a_s + f0);
  const float4* ad4 = (const float4*)(a_d + f0);
  float4 sa = as4[0], sb = as4[1];
  float4 da = ad4[0], db = ad4[1];
  float s = v[0]*sa.x + v[1]*sa.y + v[2]*sa.z + v[3]*sa.w
          + v[4]*sb.x + v[5]*sb.y + v[6]*sb.z + v[7]*sb.w;
  float d = v[0]*da.x + v[1]*da.y + v[2]*da.z + v[3]*da.w
          + v[4]*db.x + v[5]*db.y + v[6]*db.z + v[7]*db.w;
  #pragma unroll
  for (int o=1;o<8;o<<=1){ s += __shfl_xor(s, o); d += __shfl_xor(d, o); }
  if ((lane & 7) == 0){
    int hh = lane >> 3;
    als[n*HEADS+hh] = s;
    ald[n*HEADS+hh] = d;
  }
}

// ---------------- fused GAT: wave per node, lane = 8 features; XCD-swizzled ----------------
__global__ __launch_bounds__(256) void k_gat(const bf16* __restrict__ xs,
                                             const float* __restrict__ als,
                                             const float* __restrict__ ald,
                                             const float* __restrict__ coef,
                                             const int* __restrict__ row_ptr,
                                             const int* __restrict__ deg,
                                             const int* __restrict__ esrc,
                                             const float* __restrict__ eattr,
                                             const float* __restrict__ la,
                                             const float* __restrict__ bias,
                                             int self,
                                             bf16* __restrict__ h){
  // XCD swizzle: contiguous chunk per XCD so each XCD's L2 sees few graphs at a time
  int nwg = gridDim.x;                   // 16384, %8 == 0
  int cpx = nwg >> 3;
  int bid = blockIdx.x;
  int swz = (bid & 7)*cpx + (bid >> 3);
  int n = swz*4 + (threadIdx.x >> 6);
  int lane = threadIdx.x & 63;
  int hh = lane >> 3;                    // head of my 8 features
  int row = row_ptr[n], d = deg[n];
  int tot = d + self;
  float aldn = ald[n*HEADS+hh];
  float ch = coef[hh];
  float lan = la[n];

  float m = -1e30f;
  for (int i=0;i<tot;i++){
    int s; float at;
    if (i<d){ s = esrc[row+i]; at = eattr[row+i]; }
    else    { s = n;           at = lan; }
    float raw = als[s*HEADS+hh] + aldn + at*ch;
    raw = raw > 0.f ? raw : NEG*raw;
    m = fmaxf(m, raw);
  }
  float ssum = 0.f;
  float acc[8] = {};
  for (int i=0;i<tot;i++){
    int s; float at;
    if (i<d){ s = esrc[row+i]; at = eattr[row+i]; }
    else    { s = n;           at = lan; }
    float raw = als[s*HEADS+hh] + aldn + at*ch;
    raw = raw > 0.f ? raw : NEG*raw;
    float p = expf(raw - m);
    ssum += p;
    short8 v = ((const short8*)(xs + (size_t)s*FDIM))[lane];
    #pragma unroll
    for (int j=0;j<8;j++) acc[j] += p * bf(v[j]);
  }
  float inv = 1.f / fmaxf(ssum, 1e-16f);
  const float4* b4 = (const float4*)bias;
  float4 ba = b4[lane*2], bb = b4[lane*2+1];
  float bias8[8] = {ba.x,ba.y,ba.z,ba.w,bb.x,bb.y,bb.z,bb.w};
  short8 r;
  #pragma unroll
  for (int j=0;j<8;j++){
    float o = acc[j]*inv + bias8[j];
    bf16 b = __float2bfloat16(o > 0.f ? o : 0.f);
    r[j] = *(short*)&b;
  }
  ((short8*)(h + (size_t)n*FDIM))[lane] = r;
}

// ---------------- MFMA GEMM + fused attention logits ----------------
// C[M,N](bf16) = A[M,K](bf16) @ (Whi+Wlo)^T ; als/ald += per-head dots (pre-zeroed).
// 1-D grid 2048, XCD-chunk swizzle (N-minor) so the 4 N-tiles sharing an A-panel
// run temporally adjacent on one XCD -> A re-reads become L2 hits.
__global__ __launch_bounds__(256) void gemm_mfma(const bf16* __restrict__ A,
                                                 const bf16* __restrict__ Whi,
                                                 const bf16* __restrict__ Wlo,
                                                 const float* __restrict__ a_s,
                                                 const float* __restrict__ a_d,
                                                 bf16* __restrict__ C,
                                                 float* __restrict__ als,
                                                 float* __restrict__ ald,
                                                 int M, int N, int K){
  __shared__ short As[128*64];
  __shared__ short Bh[128*64];
  __shared__ short Bl[128*64];
  int bid = blockIdx.x;
  int wk = ((bid & 7) << 8) | (bid >> 3);    // XCD chunk swizzle (2048 = 8*256)
  const int bm = (wk >> 2)*128, bn = (wk & 3)*128;
  const int tid = threadIdx.x;
  const int lane = tid & 63;
  const int w = tid >> 6;
  const int wm = (w >> 1)*64, wn = (w & 1)*64;
  const int lr = lane & 15;
  const int lk = lane >> 4;

  f32x4 acc[4][4] = {};

  for (int k0 = 0; k0 < K; k0 += 64){
    #pragma unroll
    for (int is = 0; is < 4; ++is){
      int i = is*256 + tid;            // granule id: row r, granule g
      int r = i >> 3, g = i & 7;
      int gs = g ^ (r & 7);            // inverse swizzle on source
      gload16(&As[i*8], A   + (size_t)(bm+r)*K + k0 + gs*8);
      gload16(&Bh[i*8], Whi + (size_t)(bn+r)*K + k0 + gs*8);
      gload16(&Bl[i*8], Wlo + (size_t)(bn+r)*K + k0 + gs*8);
    }
    __syncthreads();
    #pragma unroll
    for (int kk = 0; kk < 2; ++kk){
      short8 af[4], bhf[4], blf[4];
      #pragma unroll
      for (int mi=0; mi<4; ++mi){
        int row = wm + mi*16 + lr;
        int g = (kk*4 + lk) ^ (row & 7);
        af[mi] = *(const short8*)&As[row*64 + g*8];
      }
      #pragma unroll
      for (int ni=0; ni<4; ++ni){
        int row = wn + ni*16 + lr;
        int g = (kk*4 + lk) ^ (row & 7);
        bhf[ni] = *(const short8*)&Bh[row*64 + g*8];
        blf[ni] = *(const short8*)&Bl[row*64 + g*8];
      }
      #pragma unroll
      for (int mi=0; mi<4; ++mi)
        #pragma unroll
        for (int ni=0; ni<4; ++ni){
          acc[mi][ni] = __builtin_amdgcn_mfma_f32_16x16x32_bf16(af[mi], bhf[ni], acc[mi][ni], 0,0,0);
          acc[mi][ni] = __builtin_amdgcn_mfma_f32_16x16x32_bf16(af[mi], blf[ni], acc[mi][ni], 0,0,0);
        }
    }
    __syncthreads();
  }

  // C write: col = lane&15, row = (lane>>4)*4 + reg   (m89 layout)
  #pragma unroll
  for (int mi=0; mi<4; ++mi)
    #pragma unroll
    for (int ni=0; ni<4; ++ni){
      int col = bn + wn + ni*16 + lr;
      #pragma unroll
      for (int r=0; r<4; ++r){
        int rowg = bm + wm + mi*16 + lk*4 + r;
        C[(size_t)rowg*N + col] = __float2bfloat16(acc[mi][ni][r]);
      }
    }

  // Fused attention logits: this wave's 64 cols = exactly one head block.
  int hh = (bn + wn) >> 6;
  float as_c[4], ad_c[4];
  #pragma unroll
  for (int ni=0; ni<4; ++ni){
    int c = ni*16 + lr;
    as_c[ni] = a_s[hh*64 + c];
    ad_c[ni] = a_d[hh*64 + c];
  }
  #pragma unroll
  for (int mi=0; mi<4; ++mi)
    #pragma unroll
    for (int r=0; r<4; ++r){
      float s = acc[mi][0][r]*as_c[0] + acc[mi][1][r]*as_c[1]
              + acc[mi][2][r]*as_c[2] + acc[mi][3][r]*as_c[3];
      float d = acc[mi][0][r]*ad_c[0] + acc[mi][1][r]*ad_c[1]
              + acc[mi][2][r]*ad_c[2] + acc[mi][3][r]*ad_c[3];
      #pragma unroll
      for (int o=1;o<16;o<<=1){ s += __shfl_xor(s, o); d += __shfl_xor(d, o); }
      if (lr == 0){
        int rowg = bm + wm + mi*16 + lk*4 + r;
        atomicAdd(&als[rowg*HEADS+hh], s);
        atomicAdd(&ald[rowg*HEADS+hh], d);
      }
    }
}

// ---------------- head part 1: per-16-node partial sums (vectorized) ----------------
__global__ __launch_bounds__(256) void k_gemb1(const bf16* __restrict__ h, float* __restrict__ pgemb){
  int gs_ = blockIdx.x;                 // g*8+s, 1024 blocks
  int g = gs_ >> 3, s = gs_ & 7;
  int t = threadIdx.x;
  int c = t & 63, rg = t >> 6;          // 4 row-groups of 16 rows
  const bf16* base = h + ((size_t)(g*NPG_ + s*64 + rg*16))*FDIM;
  float acc[8] = {};
  #pragma unroll 4
  for (int i=0;i<16;i++){
    short8 v = ((const short8*)(base + (size_t)i*FDIM))[c];
    #pragma unroll
    for (int j=0;j<8;j++) acc[j] += bf(v[j]);
  }
  float* dst = pgemb + ((size_t)(gs_*4 + rg))*FDIM + c*8;
  float4 lo = {acc[0],acc[1],acc[2],acc[3]};
  float4 hi = {acc[4],acc[5],acc[6],acc[7]};
  *(float4*)dst = lo;
  *(float4*)(dst+4) = hi;
}

// ---------------- head part 2: mean + FC1 + ReLU + FC2 fused, 4-way K-split ----------------
__global__ __launch_bounds__(1024) void k_head(const bf16* __restrict__ h,
                                               const float* __restrict__ pgemb,
                                               const float* __restrict__ fc1w,
                                               const float* __restrict__ fc1b,
                                               const float* __restrict__ fc2w,
                                               const float* __restrict__ fc2b,
                                               float* __restrict__ out){
  __shared__ float ge[FDIM];            // graph embedding (mean)
  __shared__ float ag[8][FDIM];         // 8 agent rows
  __shared__ float ps[2][8][257];       // agent-part partials (q=0,1)
  __shared__ float gs2[2][256];         // graph-part partials (q=2,3)
  __shared__ float f1[8][256];          // fc1 activations
  int g = blockIdx.x, t = threadIdx.x;

  if (t < FDIM){
    float s = 0.f;
    const float* p = pgemb + (size_t)g*32*FDIM + t;
    #pragma unroll
    for (int c=0;c<32;c++) s += p[(size_t)c*FDIM];
    ge[t] = s * (1.f/NPG_);
  } else {
    int i = t - FDIM;                   // 512 units: 8 rows x 64 short8
    int r = i >> 6, c = i & 63;
    short8 v = ((const short8*)(h + (size_t)(g*NPG_ + r)*FDIM))[c];
    #pragma unroll
    for (int j=0;j<8;j++) ag[r][c*8+j] = bf(v[j]);
  }
  __syncthreads();

  int col = t & 255, q = t >> 8;
  if (q < 2){
    float acc[8] = {};
    int kbeg = q*256;
    for (int k = kbeg; k < kbeg+256; k += 4){
      float w0 = fc1w[(k+0)*256+col];
      float w1 = fc1w[(k+1)*256+col];
      float w2 = fc1w[(k+2)*256+col];
      float w3 = fc1w[(k+3)*256+col];
      #pragma unroll
      for (int r=0;r<8;r++){
        float4 a = *(const float4*)&ag[r][k];
        acc[r] += a.x*w0 + a.y*w1 + a.z*w2 + a.w*w3;
      }
    }
    #pragma unroll
    for (int r=0;r<8;r++) ps[q][r][col] = acc[r];
  } else {
    float gacc = 0.f;
    int kbeg = (q-2)*256;
    for (int k = kbeg; k < kbeg+256; k += 4){
      float v0 = fc1w[(FDIM+k+0)*256+col];
      float v1 = fc1w[(FDIM+k+1)*256+col];
      float v2 = fc1w[(FDIM+k+2)*256+col];
      float v3 = fc1w[(FDIM+k+3)*256+col];
      float4 gv = *(const float4*)&ge[k];
      gacc += gv.x*v0 + gv.y*v1 + gv.z*v2 + gv.w*v3;
    }
    gs2[q-2][col] = gacc;
  }
  __syncthreads();

  if (t < 256){
    float b = fc1b[t] + gs2[0][t] + gs2[1][t];
    #pragma unroll
    for (int r=0;r<8;r++)
      f1[r][t] = fmaxf(ps[0][r][t] + ps[1][r][t] + b, 0.f);
  }
  __syncthreads();

  if (t < 128){
    int r = t >> 4, o = (t >> 3) & 1, l = t & 7;
    float s = 0.f;
    for (int k = l; k < 256; k += 8) s += f1[r][k] * fc2w[k*2+o];
    #pragma unroll
    for (int off=4; off; off>>=1) s += __shfl_down(s, off);
    if (l == 0) out[(g*8 + r)*2 + o] = s + fc2b[o];
  }
}

extern "C" void kernel_launch(void* const* d_in, const int* in_sizes, int n_in,
                              void* d_out, int out_size, void* d_ws, size_t ws_size,
                              hipStream_t stream)
{
  const float* x    = (const float*)d_in[0];
  const int*   ei   = (const int*)  d_in[1];
  const float* ea   = (const float*)d_in[2];
  const float* Wl[3]  = {(const float*)d_in[3],  (const float*)d_in[9],  (const float*)d_in[15]};
  const float* Bl[3]  = {(const float*)d_in[4],  (const float*)d_in[10], (const float*)d_in[16]};
  const float* ASl[3] = {(const float*)d_in[5],  (const float*)d_in[11], (const float*)d_in[17]};
  const float* ADl[3] = {(const float*)d_in[6],  (const float*)d_in[12], (const float*)d_in[18]};
  const float* WEl[3] = {(const float*)d_in[7],  (const float*)d_in[13], (const float*)d_in[19]};
  const float* AEl[3] = {(const float*)d_in[8],  (const float*)d_in[14], (const float*)d_in[20]};
  const float* FC1W = (const float*)d_in[21];
  const float* FC1B = (const float*)d_in[22];
  const float* FC2W = (const float*)d_in[23];
  const float* FC2B = (const float*)d_in[24];
  float* out = (float*)d_out;
  (void)in_sizes; (void)n_in;

  char* ws = (char*)d_ws;
  size_t off = 0;
  auto alloc = [&](size_t bytes)->char*{
    char* p = ws + off;
    off = (off + bytes + 255) & ~(size_t)255;
    return p;
  };
  bf16*  h       = (bf16*) alloc((size_t)NN*FDIM*2);    // 64 MB
  bf16*  xs      = (bf16*) alloc((size_t)NN*FDIM*2);    // 64 MB
  float* als     = (float*)alloc((size_t)NN*HEADS*4);   // 2 MB
  float* ald     = (float*)alloc((size_t)NN*HEADS*4);   // 2 MB
  float* la      = (float*)alloc((size_t)NN*4);
  float* ssum    = (float*)alloc((size_t)NN*4);
  int*   deg     = (int*)  alloc((size_t)NN*4);
  int*   cursor  = (int*)  alloc((size_t)NN*4);
  int*   row_ptr = (int*)  alloc((size_t)NN*4);
  int*   incl    = (int*)  alloc((size_t)NN*4);
  int*   bsum    = (int*)  alloc(64*4);
  int*   esrc    = (int*)  alloc((size_t)ETOT*4);
  float* eattr   = (float*)alloc((size_t)ETOT*4);
  float* coef    = (float*)alloc(3*HEADS*4);
  bf16*  whi     = (bf16*) alloc((size_t)2*FDIM*FDIM*2);  // layers 2,3 hi
  bf16*  wlo     = (bf16*) alloc((size_t)2*FDIM*FDIM*2);  // layers 2,3 lo
  float* pgemb   = (float*)alloc((size_t)NGRAPH*32*FDIM*4); // 8 MB

  if (off > ws_size){
    k_sentinel<<<(out_size+255)/256, 256, 0, stream>>>(out, out_size);
    return;
  }

  // ---- CSR build (shared across layers) ----
  k_zero <<<(NN+255)/256, 256, 0, stream>>>(deg, cursor, ssum);
  k_count<<<(ETOT+255)/256, 256, 0, stream>>>(ei, ea, deg, ssum);
  k_scan1<<<64, 1024, 0, stream>>>(deg, incl, bsum);
  k_scan2<<<1, 64, 0, stream>>>(bsum);
  k_scan3<<<(NN+255)/256, 256, 0, stream>>>(incl, bsum, deg, row_ptr, ssum, la);
  k_fill <<<(ETOT+255)/256, 256, 0, stream>>>(ei, ea, row_ptr, cursor, esrc, eattr);

  k_coef3<<<3, 512, 0, stream>>>(WEl[0], AEl[0], WEl[1], AEl[1], WEl[2], AEl[2], coef);
  k_wsplit<<<(2*FDIM*FDIM+255)/256, 256, 0, stream>>>(Wl[1], Wl[2], whi, wlo);

  // ---- layer 1 (no self loops), linear + logits fused ----
  k_lin1_attn<<<NN/4, 256, 0, stream>>>(x, Wl[0], ASl[0], ADl[0], xs, als, ald);
  k_gat<<<NN/4, 256, 0, stream>>>(xs, als, ald, coef, row_ptr, deg, esrc, eattr, la, Bl[0], 0, h);

  // ---- layers 2,3 (with self loops); attn logits fused into GEMM epilogue ----
  for (int l=1;l<3;l++){
    hipMemsetAsync(als, 0, (size_t)NN*HEADS*4, stream);
    hipMemsetAsync(ald, 0, (size_t)NN*HEADS*4, stream);
    gemm_mfma<<<2048, 256, 0, stream>>>(h,
        whi + (size_t)(l-1)*FDIM*FDIM, wlo + (size_t)(l-1)*FDIM*FDIM,
        ASl[l], ADl[l], xs, als, ald, NN, FDIM, FDIM);
    k_gat<<<NN/4, 256, 0, stream>>>(xs, als, ald, coef + l*HEADS, row_ptr, deg, esrc, eattr, la, Bl[l], 1, h);
  }

  // ---- head ----
  k_gemb1<<<NGRAPH*8, 256, 0, stream>>>(h, pgemb);
  k_head <<<NGRAPH, 1024, 0, stream>>>(h, pgemb, FC1W, FC1B, FC2W, FC2B, out);
}

// Round 6
// 293.508 us; speedup vs baseline: 1.4328x; 1.4328x over previous
//
#include <hip/hip_runtime.h>
#include <hip/hip_bf16.h>
#include <math.h>

#define NGRAPH 128
#define NPG_   512
#define NN     (NGRAPH*NPG_)     // 65536 nodes
#define EPG    504
#define ETOT   (NGRAPH*EPG)      // 64512 real edges
#define HEADS  8
#define FDIM   512
#define NEG    0.2f

typedef __hip_bfloat16 bf16;
typedef __attribute__((ext_vector_type(8))) short short8;   // 8 bf16 = 4 VGPR
typedef __attribute__((ext_vector_type(4))) float f32x4;

static __device__ __forceinline__ float bf(short s){
  union { unsigned u; float f; } c; c.u = ((unsigned)(unsigned short)s) << 16; return c.f;
}

static __device__ __forceinline__ void gload16(void* lds, const void* g){
  __builtin_amdgcn_global_load_lds((const __attribute__((address_space(1))) void*)g,
                                   (__attribute__((address_space(3))) void*)lds, 16, 0, 0);
}

// ---------------- workspace guard ----------------
__global__ void k_sentinel(float* out, int n){
  int i = blockIdx.x*blockDim.x + threadIdx.x;
  if (i < n) out[i] = 12345.0f;
}

// ---------------- CSR build ----------------
__global__ void k_zero(int* __restrict__ deg, int* __restrict__ cursor, float* __restrict__ ssum){
  int i = blockIdx.x*blockDim.x + threadIdx.x;
  if (i < NN){ deg[i]=0; cursor[i]=0; ssum[i]=0.f; }
}

__global__ void k_count(const int* __restrict__ ei, const float* __restrict__ ea,
                        int* __restrict__ deg, float* __restrict__ ssum){
  int e = blockIdx.x*blockDim.x + threadIdx.x;
  if (e >= ETOT) return;
  int g = e / EPG;
  int dst = ei[e*2+1] + g*NPG_;
  atomicAdd(&deg[dst], 1);
  atomicAdd(&ssum[dst], ea[e]);
}

__global__ __launch_bounds__(1024) void k_scan1(const int* __restrict__ deg,
                                                int* __restrict__ incl, int* __restrict__ bsum){
  __shared__ int tmp[1024];
  int t = threadIdx.x;
  int i = blockIdx.x*1024 + t;
  tmp[t] = deg[i];
  __syncthreads();
  for (int o=1;o<1024;o<<=1){
    int v = (t>=o) ? tmp[t-o] : 0;
    __syncthreads();
    tmp[t] += v;
    __syncthreads();
  }
  incl[i] = tmp[t];
  if (t==1023) bsum[blockIdx.x] = tmp[1023];
}

__global__ void k_scan2(int* __restrict__ bsum){   // 1 block, 64 threads
  __shared__ int tmp[64];
  int t = threadIdx.x;
  tmp[t] = bsum[t];
  __syncthreads();
  for (int o=1;o<64;o<<=1){
    int v = (t>=o) ? tmp[t-o] : 0;
    __syncthreads();
    tmp[t] += v;
    __syncthreads();
  }
  bsum[t] = tmp[t];
}

__global__ void k_scan3(const int* __restrict__ incl, const int* __restrict__ bsum,
                        const int* __restrict__ deg, int* __restrict__ row_ptr,
                        const float* __restrict__ ssum, float* __restrict__ la){
  int i = blockIdx.x*blockDim.x + threadIdx.x;
  if (i >= NN) return;
  int b = i >> 10;
  int off = (b>0) ? bsum[b-1] : 0;
  row_ptr[i] = incl[i] - deg[i] + off;   // exclusive prefix
  la[i] = ssum[i] / fmaxf((float)deg[i], 1.f);
}

__global__ void k_fill(const int* __restrict__ ei, const float* __restrict__ ea,
                       const int* __restrict__ row_ptr, int* __restrict__ cursor,
                       int* __restrict__ esrc, float* __restrict__ eattr){
  int e = blockIdx.x*blockDim.x + threadIdx.x;
  if (e >= ETOT) return;
  int g = e / EPG;
  int src = ei[e*2]   + g*NPG_;
  int dst = ei[e*2+1] + g*NPG_;
  int slot = atomicAdd(&cursor[dst], 1);
  int p = row_ptr[dst] + slot;
  esrc[p]  = src;
  eattr[p] = ea[e];
}

// ---------------- coefE[h] = sum_c We[h*64+c]*ae[h*64+c], 3 layers in one ----------------
__global__ __launch_bounds__(512) void k_coef3(const float* __restrict__ We0, const float* __restrict__ ae0,
                                               const float* __restrict__ We1, const float* __restrict__ ae1,
                                               const float* __restrict__ We2, const float* __restrict__ ae2,
                                               float* __restrict__ coef){
  int l = blockIdx.x;
  const float* We = l==0 ? We0 : (l==1 ? We1 : We2);
  const float* ae = l==0 ? ae0 : (l==1 ? ae1 : ae2);
  int tid = threadIdx.x;                 // 8 waves, wave per head
  float v = We[tid]*ae[tid];
  #pragma unroll
  for (int o=32;o>0;o>>=1) v += __shfl_down(v, o);
  if ((tid & 63) == 0) coef[l*HEADS + (tid>>6)] = v;
}

// ---------------- W -> transposed bf16: Wt[n][k], layers 2,3 ----------------
__global__ void k_wt(const float* __restrict__ W1, const float* __restrict__ W2,
                     bf16* __restrict__ wt){
  int idx = blockIdx.x*blockDim.x + threadIdx.x;     // l*256K + n*512 + k
  if (idx >= 2*FDIM*FDIM) return;
  int l = idx >> 18;
  int r = idx & (FDIM*FDIM-1);
  int n = r >> 9, k = r & 511;
  const float* W = l ? W2 : W1;
  wt[idx] = __float2bfloat16(W[k*FDIM + n]);         // transposed read (L2-resident 1MB)
}

// ---------------- layer1 linear (K=3) + attention logits fused: wave per node ----------------
__global__ __launch_bounds__(256) void k_lin1_attn(const float* __restrict__ x,
                                                   const float* __restrict__ W,
                                                   const float* __restrict__ a_s,
                                                   const float* __restrict__ a_d,
                                                   bf16* __restrict__ xs,
                                                   float* __restrict__ als,
                                                   float* __restrict__ ald){
  int n = blockIdx.x*4 + (threadIdx.x >> 6);
  int lane = threadIdx.x & 63;
  int f0 = lane << 3;
  const float* xr = x + n*3;
  float x0 = xr[0], x1 = xr[1], x2 = xr[2];
  float v[8];
  short8 r;
  #pragma unroll
  for (int j=0;j<8;j++){
    v[j] = x0*W[f0+j] + x1*W[FDIM+f0+j] + x2*W[2*FDIM+f0+j];
    bf16 b = __float2bfloat16(v[j]);
    r[j] = *(short*)&b;
  }
  ((short8*)(xs + (size_t)n*FDIM))[lane] = r;
  const float4* as4 = (const float4*)(a_s + f0);
  const float4* ad4 = (const float4*)(a_d + f0);
  float4 sa = as4[0], sb = as4[1];
  float4 da = ad4[0], db = ad4[1];
  float s = v[0]*sa.x + v[1]*sa.y + v[2]*sa.z + v[3]*sa.w
          + v[4]*sb.x + v[5]*sb.y + v[6]*sb.z + v[7]*sb.w;
  float d = v[0]*da.x + v[1]*da.y + v[2]*da.z + v[3]*da.w
          + v[4]*db.x + v[5]*db.y + v[6]*db.z + v[7]*db.w;
  #pragma unroll
  for (int o=1;o<8;o<<=1){ s += __shfl_xor(s, o); d += __shfl_xor(d, o); }
  if ((lane & 7) == 0){
    int hh = lane >> 3;
    als[n*HEADS+hh] = s;
    ald[n*HEADS+hh] = d;
  }
}

// ---------------- per-node attention logits: wave per node (layers 2,3) ----------------
__global__ __launch_bounds__(256) void k_attn_node(const bf16* __restrict__ xs,
                                                   const float* __restrict__ a_s,
                                                   const float* __restrict__ a_d,
                                                   float* __restrict__ als,
                                                   float* __restrict__ ald){
  int n = blockIdx.x*4 + (threadIdx.x >> 6);
  int lane = threadIdx.x & 63;
  short8 v = ((const short8*)(xs + (size_t)n*FDIM))[lane];
  const float4* as4 = (const float4*)a_s;
  const float4* ad4 = (const float4*)a_d;
  float4 sa = as4[lane*2], sb = as4[lane*2+1];
  float4 da = ad4[lane*2], db = ad4[lane*2+1];
  float s = bf(v[0])*sa.x + bf(v[1])*sa.y + bf(v[2])*sa.z + bf(v[3])*sa.w
          + bf(v[4])*sb.x + bf(v[5])*sb.y + bf(v[6])*sb.z + bf(v[7])*sb.w;
  float d = bf(v[0])*da.x + bf(v[1])*da.y + bf(v[2])*da.z + bf(v[3])*da.w
          + bf(v[4])*db.x + bf(v[5])*db.y + bf(v[6])*db.z + bf(v[7])*db.w;
  #pragma unroll
  for (int o=1;o<8;o<<=1){ s += __shfl_xor(s, o); d += __shfl_xor(d, o); }
  if ((lane & 7) == 0){
    int hh = lane >> 3;
    als[n*HEADS+hh] = s;
    ald[n*HEADS+hh] = d;
  }
}

// ---------------- fused GAT: single-pass online softmax; wave per node ----------------
__global__ __launch_bounds__(256) void k_gat(const bf16* __restrict__ xs,
                                             const float* __restrict__ als,
                                             const float* __restrict__ ald,
                                             const float* __restrict__ coef,
                                             const int* __restrict__ row_ptr,
                                             const int* __restrict__ deg,
                                             const int* __restrict__ esrc,
                                             const float* __restrict__ eattr,
                                             const float* __restrict__ la,
                                             const float* __restrict__ bias,
                                             int self,
                                             bf16* __restrict__ h){
  // XCD swizzle: contiguous chunk per XCD so each XCD's L2 sees few graphs at a time
  int nwg = gridDim.x;                   // 16384, %8 == 0
  int cpx = nwg >> 3;
  int bid = blockIdx.x;
  int swz = (bid & 7)*cpx + (bid >> 3);
  int n = swz*4 + (threadIdx.x >> 6);
  int lane = threadIdx.x & 63;
  int hh = lane >> 3;                    // head of my 8 features
  int row = row_ptr[n], d = deg[n];
  int tot = d + self;
  float aldn = ald[n*HEADS+hh];
  float ch = coef[hh];
  float lan = la[n];

  float m = -1e30f, ssum = 0.f;
  float acc[8] = {};
  for (int i=0;i<tot;i++){
    int s; float at;
    if (i<d){ s = esrc[row+i]; at = eattr[row+i]; }
    else    { s = n;           at = lan; }
    float raw = als[s*HEADS+hh] + aldn + at*ch;
    raw = raw > 0.f ? raw : NEG*raw;
    float mn = fmaxf(m, raw);
    float scale = __expf(m - mn);        // 1 if max unchanged; 0 on first iter
    float p = __expf(raw - mn);
    ssum = ssum*scale + p;
    short8 v = ((const short8*)(xs + (size_t)s*FDIM))[lane];
    #pragma unroll
    for (int j=0;j<8;j++) acc[j] = acc[j]*scale + p*bf(v[j]);
    m = mn;
  }
  float inv = 1.f / fmaxf(ssum, 1e-16f);
  const float4* b4 = (const float4*)bias;
  float4 ba = b4[lane*2], bb = b4[lane*2+1];
  float bias8[8] = {ba.x,ba.y,ba.z,ba.w,bb.x,bb.y,bb.z,bb.w};
  short8 r;
  #pragma unroll
  for (int j=0;j<8;j++){
    float o = acc[j]*inv + bias8[j];
    bf16 b = __float2bfloat16(o > 0.f ? o : 0.f);
    r[j] = *(short*)&b;
  }
  ((short8*)(h + (size_t)n*FDIM))[lane] = r;
}

// ---------------- MFMA GEMM: C[M,N](bf16) = A[M,K](bf16) @ Wt^T, single-B ----------------
// 1-D grid 2048, XCD-chunk swizzle (N-minor): the 4 N-tiles sharing an A-panel run
// temporally adjacent on one XCD -> A re-reads are L2 hits. 32 KB LDS -> 5 blocks/CU.
__global__ __launch_bounds__(256) void gemm_mfma(const bf16* __restrict__ A,
                                                 const bf16* __restrict__ Wt,
                                                 bf16* __restrict__ C,
                                                 int M, int N, int K){
  __shared__ short As[128*64];
  __shared__ short Bs[128*64];
  int bid = blockIdx.x;
  int wk = ((bid & 7) << 8) | (bid >> 3);    // XCD chunk swizzle (2048 = 8*256)
  const int bm = (wk >> 2)*128, bn = (wk & 3)*128;
  const int tid = threadIdx.x;
  const int lane = tid & 63;
  const int w = tid >> 6;
  const int wm = (w >> 1)*64, wn = (w & 1)*64;
  const int lr = lane & 15;
  const int lk = lane >> 4;

  f32x4 acc[4][4] = {};

  for (int k0 = 0; k0 < K; k0 += 64){
    #pragma unroll
    for (int is = 0; is < 4; ++is){
      int i = is*256 + tid;            // granule id: row r, granule g
      int r = i >> 3, g = i & 7;
      int gs = g ^ (r & 7);            // inverse swizzle on source
      gload16(&As[i*8], A  + (size_t)(bm+r)*K + k0 + gs*8);
      gload16(&Bs[i*8], Wt + (size_t)(bn+r)*K + k0 + gs*8);
    }
    __syncthreads();
    #pragma unroll
    for (int kk = 0; kk < 2; ++kk){
      short8 af[4], bfr[4];
      #pragma unroll
      for (int mi=0; mi<4; ++mi){
        int row = wm + mi*16 + lr;
        int g = (kk*4 + lk) ^ (row & 7);
        af[mi] = *(const short8*)&As[row*64 + g*8];
      }
      #pragma unroll
      for (int ni=0; ni<4; ++ni){
        int row = wn + ni*16 + lr;
        int g = (kk*4 + lk) ^ (row & 7);
        bfr[ni] = *(const short8*)&Bs[row*64 + g*8];
      }
      #pragma unroll
      for (int mi=0; mi<4; ++mi)
        #pragma unroll
        for (int ni=0; ni<4; ++ni)
          acc[mi][ni] = __builtin_amdgcn_mfma_f32_16x16x32_bf16(af[mi], bfr[ni], acc[mi][ni], 0,0,0);
    }
    __syncthreads();
  }

  // epilogue: col = lane&15, row = (lane>>4)*4 + reg   (m89 layout)
  #pragma unroll
  for (int mi=0; mi<4; ++mi)
    #pragma unroll
    for (int ni=0; ni<4; ++ni){
      int col = bn + wn + ni*16 + lr;
      #pragma unroll
      for (int r=0; r<4; ++r){
        int rowg = bm + wm + mi*16 + lk*4 + r;
        C[(size_t)rowg*N + col] = __float2bfloat16(acc[mi][ni][r]);
      }
    }
}

// ---------------- head part 1: per-16-node partial sums (vectorized) ----------------
__global__ __launch_bounds__(256) void k_gemb1(const bf16* __restrict__ h, float* __restrict__ pgemb){
  int gs_ = blockIdx.x;                 // g*8+s, 1024 blocks
  int g = gs_ >> 3, s = gs_ & 7;
  int t = threadIdx.x;
  int c = t & 63, rg = t >> 6;          // 4 row-groups of 16 rows
  const bf16* base = h + ((size_t)(g*NPG_ + s*64 + rg*16))*FDIM;
  float acc[8] = {};
  #pragma unroll 4
  for (int i=0;i<16;i++){
    short8 v = ((const short8*)(base + (size_t)i*FDIM))[c];
    #pragma unroll
    for (int j=0;j<8;j++) acc[j] += bf(v[j]);
  }
  float* dst = pgemb + ((size_t)(gs_*4 + rg))*FDIM + c*8;
  float4 lo = {acc[0],acc[1],acc[2],acc[3]};
  float4 hi = {acc[4],acc[5],acc[6],acc[7]};
  *(float4*)dst = lo;
  *(float4*)(dst+4) = hi;
}

// ---------------- head part 2: mean + FC1 + ReLU + FC2 fused, 4-way K-split ----------------
__global__ __launch_bounds__(1024) void k_head(const bf16* __restrict__ h,
                                               const float* __restrict__ pgemb,
                                               const float* __restrict__ fc1w,
                                               const float* __restrict__ fc1b,
                                               const float* __restrict__ fc2w,
                                               const float* __restrict__ fc2b,
                                               float* __restrict__ out){
  __shared__ float ge[FDIM];            // graph embedding (mean)
  __shared__ float ag[8][FDIM];         // 8 agent rows
  __shared__ float ps[2][8][257];       // agent-part partials (q=0,1)
  __shared__ float gs2[2][256];         // graph-part partials (q=2,3)
  __shared__ float f1[8][256];          // fc1 activations
  int g = blockIdx.x, t = threadIdx.x;

  if (t < FDIM){
    float s = 0.f;
    const float* p = pgemb + (size_t)g*32*FDIM + t;
    #pragma unroll
    for (int c=0;c<32;c++) s += p[(size_t)c*FDIM];
    ge[t] = s * (1.f/NPG_);
  } else {
    int i = t - FDIM;                   // 512 units: 8 rows x 64 short8
    int r = i >> 6, c = i & 63;
    short8 v = ((const short8*)(h + (size_t)(g*NPG_ + r)*FDIM))[c];
    #pragma unroll
    for (int j=0;j<8;j++) ag[r][c*8+j] = bf(v[j]);
  }
  __syncthreads();

  int col = t & 255, q = t >> 8;
  if (q < 2){
    float acc[8] = {};
    int kbeg = q*256;
    for (int k = kbeg; k < kbeg+256; k += 4){
      float w0 = fc1w[(k+0)*256+col];
      float w1 = fc1w[(k+1)*256+col];
      float w2 = fc1w[(k+2)*256+col];
      float w3 = fc1w[(k+3)*256+col];
      #pragma unroll
      for (int r=0;r<8;r++){
        float4 a = *(const float4*)&ag[r][k];
        acc[r] += a.x*w0 + a.y*w1 + a.z*w2 + a.w*w3;
      }
    }
    #pragma unroll
    for (int r=0;r<8;r++) ps[q][r][col] = acc[r];
  } else {
    float gacc = 0.f;
    int kbeg = (q-2)*256;
    for (int k = kbeg; k < kbeg+256; k += 4){
      float v0 = fc1w[(FDIM+k+0)*256+col];
      float v1 = fc1w[(FDIM+k+1)*256+col];
      float v2 = fc1w[(FDIM+k+2)*256+col];
      float v3 = fc1w[(FDIM+k+3)*256+col];
      float4 gv = *(const float4*)&ge[k];
      gacc += gv.x*v0 + gv.y*v1 + gv.z*v2 + gv.w*v3;
    }
    gs2[q-2][col] = gacc;
  }
  __syncthreads();

  if (t < 256){
    float b = fc1b[t] + gs2[0][t] + gs2[1][t];
    #pragma unroll
    for (int r=0;r<8;r++)
      f1[r][t] = fmaxf(ps[0][r][t] + ps[1][r][t] + b, 0.f);
  }
  __syncthreads();

  if (t < 128){
    int r = t >> 4, o = (t >> 3) & 1, l = t & 7;
    float s = 0.f;
    for (int k = l; k < 256; k += 8) s += f1[r][k] * fc2w[k*2+o];
    #pragma unroll
    for (int off=4; off; off>>=1) s += __shfl_down(s, off);
    if (l == 0) out[(g*8 + r)*2 + o] = s + fc2b[o];
  }
}

extern "C" void kernel_launch(void* const* d_in, const int* in_sizes, int n_in,
                              void* d_out, int out_size, void* d_ws, size_t ws_size,
                              hipStream_t stream)
{
  const float* x    = (const float*)d_in[0];
  const int*   ei   = (const int*)  d_in[1];
  const float* ea   = (const float*)d_in[2];
  const float* Wl[3]  = {(const float*)d_in[3],  (const float*)d_in[9],  (const float*)d_in[15]};
  const float* Bl[3]  = {(const float*)d_in[4],  (const float*)d_in[10], (const float*)d_in[16]};
  const float* ASl[3] = {(const float*)d_in[5],  (const float*)d_in[11], (const float*)d_in[17]};
  const float* ADl[3] = {(const float*)d_in[6],  (const float*)d_in[12], (const float*)d_in[18]};
  const float* WEl[3] = {(const float*)d_in[7],  (const float*)d_in[13], (const float*)d_in[19]};
  const float* AEl[3] = {(const float*)d_in[8],  (const float*)d_in[14], (const float*)d_in[20]};
  const float* FC1W = (const float*)d_in[21];
  const float* FC1B = (const float*)d_in[22];
  const float* FC2W = (const float*)d_in[23];
  const float* FC2B = (const float*)d_in[24];
  float* out = (float*)d_out;
  (void)in_sizes; (void)n_in;

  char* ws = (char*)d_ws;
  size_t off = 0;
  auto alloc = [&](size_t bytes)->char*{
    char* p = ws + off;
    off = (off + bytes + 255) & ~(size_t)255;
    return p;
  };
  bf16*  h       = (bf16*) alloc((size_t)NN*FDIM*2);    // 64 MB
  bf16*  xs      = (bf16*) alloc((size_t)NN*FDIM*2);    // 64 MB
  float* als     = (float*)alloc((size_t)NN*HEADS*4);   // 2 MB
  float* ald     = (float*)alloc((size_t)NN*HEADS*4);   // 2 MB
  float* la      = (float*)alloc((size_t)NN*4);
  float* ssum    = (float*)alloc((size_t)NN*4);
  int*   deg     = (int*)  alloc((size_t)NN*4);
  int*   cursor  = (int*)  alloc((size_t)NN*4);
  int*   row_ptr = (int*)  alloc((size_t)NN*4);
  int*   incl    = (int*)  alloc((size_t)NN*4);
  int*   bsum    = (int*)  alloc(64*4);
  int*   esrc    = (int*)  alloc((size_t)ETOT*4);
  float* eattr   = (float*)alloc((size_t)ETOT*4);
  float* coef    = (float*)alloc(3*HEADS*4);
  bf16*  wt      = (bf16*) alloc((size_t)2*FDIM*FDIM*2);  // layers 2,3 transposed bf16
  float* pgemb   = (float*)alloc((size_t)NGRAPH*32*FDIM*4); // 8 MB

  if (off > ws_size){
    k_sentinel<<<(out_size+255)/256, 256, 0, stream>>>(out, out_size);
    return;
  }

  // ---- CSR build (shared across layers) ----
  k_zero <<<(NN+255)/256, 256, 0, stream>>>(deg, cursor, ssum);
  k_count<<<(ETOT+255)/256, 256, 0, stream>>>(ei, ea, deg, ssum);
  k_scan1<<<64, 1024, 0, stream>>>(deg, incl, bsum);
  k_scan2<<<1, 64, 0, stream>>>(bsum);
  k_scan3<<<(NN+255)/256, 256, 0, stream>>>(incl, bsum, deg, row_ptr, ssum, la);
  k_fill <<<(ETOT+255)/256, 256, 0, stream>>>(ei, ea, row_ptr, cursor, esrc, eattr);

  k_coef3<<<3, 512, 0, stream>>>(WEl[0], AEl[0], WEl[1], AEl[1], WEl[2], AEl[2], coef);
  k_wt<<<(2*FDIM*FDIM+255)/256, 256, 0, stream>>>(Wl[1], Wl[2], wt);

  // ---- layer 1 (no self loops), linear + logits fused ----
  k_lin1_attn<<<NN/4, 256, 0, stream>>>(x, Wl[0], ASl[0], ADl[0], xs, als, ald);
  k_gat<<<NN/4, 256, 0, stream>>>(xs, als, ald, coef, row_ptr, deg, esrc, eattr, la, Bl[0], 0, h);

  // ---- layers 2,3 (with self loops) ----
  for (int l=1;l<3;l++){
    gemm_mfma<<<2048, 256, 0, stream>>>(h, wt + (size_t)(l-1)*FDIM*FDIM, xs, NN, FDIM, FDIM);
    k_attn_node<<<NN/4, 256, 0, stream>>>(xs, ASl[l], ADl[l], als, ald);
    k_gat<<<NN/4, 256, 0, stream>>>(xs, als, ald, coef + l*HEADS, row_ptr, deg, esrc, eattr, la, Bl[l], 1, h);
  }

  // ---- head ----
  k_gemb1<<<NGRAPH*8, 256, 0, stream>>>(h, pgemb);
  k_head <<<NGRAPH, 1024, 0, stream>>>(h, pgemb, FC1W, FC1B, FC2W, FC2B, out);
}